// Round 1
// baseline (161.662 us; speedup 1.0000x reference)
//
#include <hip/hip_runtime.h>
#include <hip/hip_bf16.h>

#define KTOT   25088          // 2 * 256 * 49
#define HALF_K 12544
#define HID    512
#define SPLITK 4
#define KCHUNK (KTOT/SPLITK)  // 6272
#define KSTEPS (KCHUNK/32)    // 196

typedef __attribute__((ext_vector_type(8))) short short8;
typedef __attribute__((ext_vector_type(4))) float f32x4;

// ---------- feats [C,H,W] -> ft [map][y*32+x][c] (channel-contiguous) ----------
__global__ __launch_bounds__(256) void k_tfeat(const float* __restrict__ f1,
                                               const float* __restrict__ f2,
                                               float* __restrict__ ft) {
  __shared__ float tile[64][65];
  const int ct = blockIdx.x, yxt = blockIdx.y, map = blockIdx.z;
  const float* src = map ? f2 : f1;
  const int t = threadIdx.x, t4 = t >> 6, tl = t & 63;
#pragma unroll
  for (int pass = 0; pass < 16; ++pass) {
    int cl = pass * 4 + t4;
    tile[cl][tl] = src[(ct * 64 + cl) * 1024 + yxt * 64 + tl];
  }
  __syncthreads();
#pragma unroll
  for (int pass = 0; pass < 16; ++pass) {
    int yl = pass * 4 + t4;
    ft[(size_t)map * 262144 + (size_t)(yxt * 64 + yl) * 256 + ct * 64 + tl] = tile[tl][yl];
  }
}

// ---------- W1 [25088][512] -> W1t bf16 [512][25088'] with k' = map*12544 + p*256 + c ----------
__global__ __launch_bounds__(256) void k_tw1(const float* __restrict__ W1,
                                             __hip_bfloat16* __restrict__ W1t) {
  __shared__ float tile[64][65];
  const int ct = blockIdx.x & 3, jt = blockIdx.x >> 2;
  const int p = blockIdx.y, map = blockIdx.z;
  const int t = threadIdx.x, t4 = t >> 6, tl = t & 63;
#pragma unroll
  for (int pass = 0; pass < 16; ++pass) {
    int cl = pass * 4 + t4;
    int c = ct * 64 + cl;
    size_t krow = (size_t)map * HALF_K + (size_t)c * 49 + p;
    tile[cl][tl] = W1[krow * HID + jt * 64 + tl];
  }
  __syncthreads();
#pragma unroll
  for (int pass = 0; pass < 16; ++pass) {
    int jl = pass * 4 + t4;
    int j = jt * 64 + jl;
    W1t[(size_t)j * KTOT + (size_t)map * HALF_K + p * 256 + ct * 64 + tl] =
        __float2bfloat16(tile[tl][jl]);
  }
}

// ---------- RoIAlign: one block per (map, box); thread = channel ----------
__global__ __launch_bounds__(256) void k_roi(const float* __restrict__ ft,
                                             const float* __restrict__ props,
                                             __hip_bfloat16* __restrict__ A) {
  __shared__ int ix0[14], ix1[14], iy0[14], iy1[14];
  __shared__ float lxs[14], lys[14], vxs[14], vys[14];
  const int map = blockIdx.x, n = blockIdx.y, t = threadIdx.x;
  const float sc = 1.0f / 32.0f;
  float bx1 = props[n * 4 + 0] * sc, by1 = props[n * 4 + 1] * sc;
  float bx2 = props[n * 4 + 2] * sc, by2 = props[n * 4 + 3] * sc;
  float bw = fmaxf(bx2 - bx1, 1.f) * (1.f / 7.f);
  float bh = fmaxf(by2 - by1, 1.f) * (1.f / 7.f);
  if (t < 32) {
    int i = t & 15;
    if (i < 14) {
      bool isY = t >= 16;
      float start = isY ? by1 : bx1;
      float bs = isY ? bh : bw;
      float o = start + (float)(i >> 1) * bs + ((float)(i & 1) + 0.5f) * bs * 0.5f;
      float v = (o >= -1.f && o <= 32.f) ? 1.f : 0.f;
      float oc = fminf(fmaxf(o, 0.f), 31.f);
      int i0 = (int)oc;
      int i1 = min(i0 + 1, 31);
      float l = oc - (float)i0;
      if (isY) { iy0[i] = i0; iy1[i] = i1; lys[i] = l; vys[i] = v; }
      else     { ix0[i] = i0; ix1[i] = i1; lxs[i] = l; vxs[i] = v; }
    }
  }
  __syncthreads();
  const float* base = ft + (size_t)map * 262144 + t;      // c = t
  __hip_bfloat16* out = A + (size_t)n * KTOT + map * HALF_K + t;
  for (int oy = 0; oy < 7; ++oy) {
    for (int ox = 0; ox < 7; ++ox) {
      float acc = 0.f;
#pragma unroll
      for (int s = 0; s < 4; ++s) {
        int py = oy * 2 + (s >> 1), px = ox * 2 + (s & 1);
        float w = vys[py] * vxs[px];
        int y0 = iy0[py], y1 = iy1[py]; float ly = lys[py];
        int x0 = ix0[px], x1 = ix1[px]; float lx = lxs[px];
        float f00 = base[(y0 * 32 + x0) * 256];
        float f01 = base[(y0 * 32 + x1) * 256];
        float f10 = base[(y1 * 32 + x0) * 256];
        float f11 = base[(y1 * 32 + x1) * 256];
        float v0 = f00 + (f01 - f00) * lx;
        float v1 = f10 + (f11 - f10) * lx;
        acc += w * (v0 + (v1 - v0) * ly);
      }
      out[(oy * 7 + ox) * 256] = __float2bfloat16(acc * 0.25f);
    }
  }
}

// ---------- GEMM1: parts[s] = A[64-tile] @ W1t^T[64-tile] over K-chunk ----------
__device__ __forceinline__ void gl_lds16(const __hip_bfloat16* g, __hip_bfloat16* l) {
  __builtin_amdgcn_global_load_lds((const __attribute__((address_space(1))) void*)g,
                                   (__attribute__((address_space(3))) void*)l, 16, 0, 0);
}

__global__ __launch_bounds__(256) void k_gemm1(const __hip_bfloat16* __restrict__ A,
                                               const __hip_bfloat16* __restrict__ Bt,
                                               float* __restrict__ parts, int M) {
  __shared__ __align__(16) __hip_bfloat16 As[64 * 32];
  __shared__ __align__(16) __hip_bfloat16 Bs[64 * 32];
  const int t = threadIdx.x;
  const int row0 = blockIdx.x * 64, col0 = blockIdx.y * 64;
  const size_t k0 = (size_t)blockIdx.z * KCHUNK;
  // staging: thread t covers LDS row t/4, k-slot t%4 (linear dest for global_load_lds);
  // pre-swizzled global source so reads can use slot = g ^ ((row>>1)&3)  -> 2-way banks
  const int lr = t >> 2, lg = t & 3;
  const int sg = lg ^ ((lr >> 1) & 3);
  const __hip_bfloat16* ag = A  + (size_t)(row0 + lr) * KTOT + k0 + sg * 8;
  const __hip_bfloat16* bg = Bt + (size_t)(col0 + lr) * KTOT + k0 + sg * 8;
  __hip_bfloat16* la = &As[t * 8];
  __hip_bfloat16* lb = &Bs[t * 8];

  const int lane = t & 63, w = t >> 6;
  const int wr = (w >> 1) * 32, wc = (w & 1) * 32;
  const int r = lane & 15, g = lane >> 4;
  const int ar0 = wr + r, ar1 = wr + 16 + r;
  const int br0 = wc + r, br1 = wc + 16 + r;
  const int ia0 = ar0 * 32 + (g ^ ((ar0 >> 1) & 3)) * 8;
  const int ia1 = ar1 * 32 + (g ^ ((ar1 >> 1) & 3)) * 8;
  const int ib0 = br0 * 32 + (g ^ ((br0 >> 1) & 3)) * 8;
  const int ib1 = br1 * 32 + (g ^ ((br1 >> 1) & 3)) * 8;

  f32x4 acc00 = {0.f, 0.f, 0.f, 0.f}, acc01 = {0.f, 0.f, 0.f, 0.f};
  f32x4 acc10 = {0.f, 0.f, 0.f, 0.f}, acc11 = {0.f, 0.f, 0.f, 0.f};
  for (int kt = 0; kt < KSTEPS; ++kt) {
    gl_lds16(ag, la);
    gl_lds16(bg, lb);
    ag += 32; bg += 32;
    __syncthreads();              // drains vmcnt -> LDS tiles ready
    short8 a0 = *(const short8*)&As[ia0];
    short8 a1 = *(const short8*)&As[ia1];
    short8 b0 = *(const short8*)&Bs[ib0];
    short8 b1 = *(const short8*)&Bs[ib1];
    acc00 = __builtin_amdgcn_mfma_f32_16x16x32_bf16(a0, b0, acc00, 0, 0, 0);
    acc01 = __builtin_amdgcn_mfma_f32_16x16x32_bf16(a0, b1, acc01, 0, 0, 0);
    acc10 = __builtin_amdgcn_mfma_f32_16x16x32_bf16(a1, b0, acc10, 0, 0, 0);
    acc11 = __builtin_amdgcn_mfma_f32_16x16x32_bf16(a1, b1, acc11, 0, 0, 0);
    __syncthreads();              // reads done before next staging overwrites
  }
  float* P = parts + (size_t)blockIdx.z * ((size_t)M * HID);
#pragma unroll
  for (int q = 0; q < 4; ++q) {
    int rA0 = row0 + wr + g * 4 + q;
    int rA1 = rA0 + 16;
    P[(size_t)rA0 * HID + col0 + wc + r]      = acc00[q];
    P[(size_t)rA0 * HID + col0 + wc + 16 + r] = acc01[q];
    P[(size_t)rA1 * HID + col0 + wc + r]      = acc10[q];
    P[(size_t)rA1 * HID + col0 + wc + 16 + r] = acc11[q];
  }
}

// ---------- reduce split-K partials + bias + ReLU ----------
__global__ __launch_bounds__(256) void k_epi1(const float* __restrict__ parts,
                                              const float* __restrict__ b1,
                                              float* __restrict__ h, int M) {
  int idx = blockIdx.x * 256 + threadIdx.x;
  size_t stride = (size_t)M * HID;
  int j = idx & (HID - 1);
  float s = parts[idx] + parts[idx + stride] + parts[idx + 2 * stride] +
            parts[idx + 3 * stride] + b1[j];
  h[idx] = fmaxf(s, 0.f);
}

// ---------- head: out = h @ W2 + b2, sigmoids, scatter to output layout ----------
__global__ __launch_bounds__(256) void k_head(const float* __restrict__ h,
                                              const float* __restrict__ W2,
                                              const float* __restrict__ b2,
                                              float* __restrict__ out, int N) {
  __shared__ float hrow[512];
  __shared__ float part[16][17];
  const int n = blockIdx.x, t = threadIdx.x;
  hrow[t]       = h[(size_t)n * HID + t];
  hrow[t + 256] = h[(size_t)n * HID + 256 + t];
  __syncthreads();
  int j = t & 15, kc = t >> 4;
  float a = 0.f;
  if (j < 11) {
#pragma unroll
    for (int kk = 0; kk < 32; ++kk) {
      int k = kc * 32 + kk;
      a += hrow[k] * W2[k * 11 + j];
    }
  }
  part[kc][j] = a;
  __syncthreads();
  if (t < 11) {
    float s = b2[t];
#pragma unroll
    for (int k2 = 0; k2 < 16; ++k2) s += part[k2][t];
    if (t == 0)      out[n] = 1.f / (1.f + expf(-s));
    else if (t == 1) out[N + n] = 1.f / (1.f + expf(-s));
    else if (t < 6)  out[2 * N + n * 4 + (t - 2)] = s;
    else if (t < 10) out[6 * N + n * 4 + (t - 6)] = s;
    else             out[10 * N + n] = 1.f / (1.f + expf(-s));
  }
}

extern "C" void kernel_launch(void* const* d_in, const int* in_sizes, int n_in,
                              void* d_out, int out_size, void* d_ws, size_t ws_size,
                              hipStream_t stream) {
  const float* feats1 = (const float*)d_in[0];
  const float* feats2 = (const float*)d_in[1];
  const float* props  = (const float*)d_in[2];
  const float* W1     = (const float*)d_in[3];
  const float* b1     = (const float*)d_in[4];
  const float* W2     = (const float*)d_in[5];
  const float* b2     = (const float*)d_in[6];
  float* out = (float*)d_out;
  const int N = in_sizes[2] / 4;   // 1024

  char* ws = (char*)d_ws;
  float* ft = (float*)ws;                                          // 2 MB
  __hip_bfloat16* Abuf = (__hip_bfloat16*)(ws + (2u << 20));       // N*25088*2 = 51.4 MB
  size_t offW1t = (2u << 20) + (size_t)N * KTOT * 2;
  __hip_bfloat16* W1t = (__hip_bfloat16*)(ws + offW1t);            // 25.7 MB
  size_t offParts = offW1t + (size_t)HID * KTOT * 2;
  float* parts = (float*)(ws + offParts);                          // 8 MB
  size_t offH = offParts + (size_t)SPLITK * N * HID * 4;
  float* h = (float*)(ws + offH);                                  // 2 MB

  k_tfeat<<<dim3(4, 16, 2), 256, 0, stream>>>(feats1, feats2, ft);
  k_tw1<<<dim3(32, 49, 2), 256, 0, stream>>>(W1, W1t);
  k_roi<<<dim3(2, N), 256, 0, stream>>>(ft, props, Abuf);
  k_gemm1<<<dim3(N / 64, HID / 64, SPLITK), 256, 0, stream>>>(Abuf, W1t, parts, N);
  k_epi1<<<dim3((N * HID) / 256), 256, 0, stream>>>(parts, b1, h, N);
  k_head<<<dim3(N), 256, 0, stream>>>(h, W2, b2, out, N);
}